// Round 4
// baseline (507.054 us; speedup 1.0000x reference)
//
#include <hip/hip_runtime.h>
#include <hip/hip_fp16.h>
#include <math.h>

#define PI_F 3.14159265358979323846f

// ---------------- fast atan2 (minimax deg-11, max err ~1e-5 rad) ----------------
__device__ inline float fast_atan2f(float y, float x) {
    float ax = fabsf(x), ay = fabsf(y);
    float mx = fmaxf(ax, ay);
    float mn = fminf(ax, ay);
    float a = __fdividef(mn, fmaxf(mx, 1e-30f));
    float s = a * a;
    float r = fmaf(s, fmaf(s, fmaf(s, fmaf(s, fmaf(s, -0.01172120f, 0.05265332f),
                   -0.11643287f), 0.19354346f), -0.33262347f), 0.99997726f);
    r = r * a;
    if (ay > ax) r = 1.57079632679f - r;
    if (x < 0.0f) r = PI_F - r;
    return copysignf(r, y);
}

// Rodrigues: pose (tx,ty,tz,rx,ry,rz) -> o[0..8]=R row-major, o[9..11]=t
__device__ inline void make_Rt_to(const float* __restrict__ pose, int bn, float* __restrict__ o) {
    const float* p = pose + bn * 6;
    float tx = p[0], ty = p[1], tz = p[2];
    float rx = p[3], ry = p[4], rz = p[5];
    float theta = sqrtf(rx * rx + ry * ry + rz * rz);
    float inv = __fdividef(1.0f, fmaxf(theta, 1e-8f));
    float kx = rx * inv, ky = ry * inv, kz = rz * inv;
    float s, c;
    __sincosf(theta, &s, &c);
    float oc = 1.0f - c;
    o[0] = 1.0f - oc * (ky * ky + kz * kz);
    o[1] = -s * kz + oc * kx * ky;
    o[2] =  s * ky + oc * kx * kz;
    o[3] =  s * kz + oc * kx * ky;
    o[4] = 1.0f - oc * (kx * kx + kz * kz);
    o[5] = -s * kx + oc * ky * kz;
    o[6] = -s * ky + oc * kx * kz;
    o[7] =  s * kx + oc * ky * kz;
    o[8] = 1.0f - oc * (kx * kx + ky * ky);
    o[9] = tx; o[10] = ty; o[11] = tz;
}

// ---------------- fp16 RGBx packing (8 B / pixel) ----------------
__device__ inline uint2 pack_px(float r, float g, float b) {
    __half2 a = __floats2half2_rn(r, g);
    __half2 c = __floats2half2_rn(b, 0.0f);
    uint2 u;
    u.x = *(const unsigned int*)&a;
    u.y = *(const unsigned int*)&c;
    return u;
}
__device__ inline float3 unpack_px(uint2 u) {
    __half2 a = *(const __half2*)&u.x;
    __half2 c = *(const __half2*)&u.y;
    float2 f = __half22float2(a);
    return make_float3(f.x, f.y, __low2float(c));
}

// ---------------- ONE-PASS prep: pack full-res tgt + build packed 3-level pyramid --------
// grid: 3 images x 8 batch x 512 tiles (32x32). 256 thr: r=t>>3 (row 0..31), k=t&7 (4px col)
__global__ __launch_bounds__(256) void prep_kernel(
    const float* __restrict__ ref, const float* __restrict__ tgt0, const float* __restrict__ tgt1,
    uint2* __restrict__ packF,                                      // tgt full: plane q=n*8+b, 1<<19 px
    uint2* __restrict__ pL1t, uint2* __restrict__ pL2t, uint2* __restrict__ pL3t,  // 16 planes
    uint2* __restrict__ pL1r, uint2* __restrict__ pL2r, uint2* __restrict__ pL3r)  // 8 planes
{
    int bid = blockIdx.x;
    int tile = bid & 511;
    int ib = bid >> 9;          // 0..23
    int b = ib & 7;
    int i = ib >> 3;            // 0=ref, 1=tgt0, 2=tgt1
    int ty = tile >> 5, tx = tile & 31;
    int t = threadIdx.x;
    int r = t >> 3;             // 0..31
    int k = t & 7;              // 0..7
    int y = ty * 32 + r;
    int xg = tx * 32 + k * 4;

    const float* img = (i == 0) ? ref : (i == 1) ? tgt0 : tgt1;
    float4 ch[3];
#pragma unroll
    for (int c = 0; c < 3; ++c)
        ch[c] = *(const float4*)(img + ((size_t)(b * 3 + c) << 19) + (y << 10) + xg);

    int q = (i - 1) * 8 + b;    // tgt plane (valid when i>0)
    if (i > 0) {
        uint2* o = packF + ((size_t)q << 19) + (y << 10) + xg;
        o[0] = pack_px(ch[0].x, ch[1].x, ch[2].x);
        o[1] = pack_px(ch[0].y, ch[1].y, ch[2].y);
        o[2] = pack_px(ch[0].z, ch[1].z, ch[2].z);
        o[3] = pack_px(ch[0].w, ch[1].w, ch[2].w);
    }

    // ---- L1 (2x2 mean): horizontal pairs in-thread, vertical via lane^8 ----
    float l1[3][2];
#pragma unroll
    for (int c = 0; c < 3; ++c) {
        float s0 = ch[c].x + ch[c].y;
        float s1 = ch[c].z + ch[c].w;
        l1[c][0] = (s0 + __shfl_xor(s0, 8)) * 0.25f;
        l1[c][1] = (s1 + __shfl_xor(s1, 8)) * 0.25f;
    }
    if ((r & 1) == 0) {
        int y1 = ty * 16 + (r >> 1);
        int x1 = tx * 16 + k * 2;
        uint2* dst = ((i == 0) ? pL1r + ((size_t)b << 17) : pL1t + ((size_t)q << 17)) + (y1 << 9) + x1;
        uint2 p0 = pack_px(l1[0][0], l1[1][0], l1[2][0]);
        uint2 p1 = pack_px(l1[0][1], l1[1][1], l1[2][1]);
        uint4 v; v.x = p0.x; v.y = p0.y; v.z = p1.x; v.w = p1.y;
        *(uint4*)dst = v;
    }

    // ---- L2: horizontal in-thread, vertical via lane^16 (rows r, r+2) ----
    float l2[3];
#pragma unroll
    for (int c = 0; c < 3; ++c) {
        float t2 = l1[c][0] + l1[c][1];
        l2[c] = (t2 + __shfl_xor(t2, 16)) * 0.25f;
    }
    if ((r & 3) == 0) {
        int y2 = ty * 8 + (r >> 2);
        int x2 = tx * 8 + k;
        uint2* dst = ((i == 0) ? pL2r + ((size_t)b << 15) : pL2t + ((size_t)q << 15)) + (y2 << 8) + x2;
        *dst = pack_px(l2[0], l2[1], l2[2]);
    }

    // ---- L3: horizontal via lane^1, vertical via lane^32 (rows r, r+4) ----
    float l3[3];
#pragma unroll
    for (int c = 0; c < 3; ++c) {
        float h3 = l2[c] + __shfl_xor(l2[c], 1);
        l3[c] = (h3 + __shfl_xor(h3, 32)) * 0.25f;
    }
    if (((r & 7) == 0) && ((k & 1) == 0)) {
        int y3 = ty * 4 + (r >> 3);
        int x3 = tx * 4 + (k >> 1);
        uint2* dst = ((i == 0) ? pL3r + ((size_t)b << 13) : pL3t + ((size_t)q << 13)) + (y3 << 7) + x3;
        *dst = pack_px(l3[0], l3[1], l3[2]);
    }
}

// ---------------- packed photometric body, one scale ----------------
template <int SH>
__device__ inline float photo_scale_packed(int bidl, int tid,
                                           const float* __restrict__ rrF,   // SH==0
                                           const uint2* __restrict__ rrP,   // SH>0
                                           const float* __restrict__ depth,
                                           const float* __restrict__ mask,
                                           const uint2* __restrict__ tg,    // planes q=n*8+b
                                           const float* __restrict__ pose,
                                           float* __restrict__ ldsRt) {
    constexpr int h = 512 >> SH;
    constexpr int w = 1024 >> SH;
    constexpr int LOG2W = 10 - SH;
    constexpr int LP = 19 - 2 * SH;
    constexpr float inv_count = 1.0f / (8.0f * 3.0f * h * w);

    int lidx = (bidl << 8) + tid;
    int b = lidx >> LP;  // block-uniform
    if (tid < 2) make_Rt_to(pose, b * 2 + tid, ldsRt + tid * 12);
    __syncthreads();

    int x = lidx & (w - 1);
    int y = (lidx >> LOG2W) & (h - 1);
    int pix = (y << LOG2W) + x;

    float lon = (((float)x + 0.5f) * (2.0f / (float)w) - 1.0f) * PI_F;
    float lat = -(((float)y + 0.5f) * (2.0f / (float)h) - 1.0f) * (0.5f * PI_F);
    float sl = __sinf(lon), cl = __cosf(lon);
    float slat = __sinf(lat), clat = __cosf(lat);

    float dep = depth[((size_t)b << LP) + pix];
    float X = dep * clat * sl, Y = dep * slat, Z = dep * clat * cl;

    float rc[3];
    if constexpr (SH == 0) {
#pragma unroll
        for (int c = 0; c < 3; ++c)
            rc[c] = rrF[((size_t)(b * 3 + c) << LP) + pix];
    } else {
        float3 rp = unpack_px(rrP[((size_t)b << LP) + pix]);
        rc[0] = rp.x; rc[1] = rp.y; rc[2] = rp.z;
    }

    float acc = 0.0f;
#pragma unroll
    for (int n = 0; n < 2; ++n) {
        const float* R = ldsRt + n * 12;
        float px = R[0] * X + R[1] * Y + R[2] * Z + R[9];
        float py = R[3] * X + R[4] * Y + R[5] * Z + R[10];
        float pz = R[6] * X + R[7] * Y + R[8] * Z + R[11];
        float rxz = sqrtf(px * px + pz * pz);
        float lon2 = fast_atan2f(px, pz);
        float lat2 = fast_atan2f(py, rxz);   // == asin(clip(py/norm))
        float gx = (lon2 * (1.0f / PI_F) + 1.0f) * 0.5f * (float)(w - 1);
        float gy = (lat2 * (2.0f / PI_F) + 1.0f) * 0.5f * (float)(h - 1);
        float x0f = floorf(gx), y0f = floorf(gy);
        float fx = gx - x0f, fy = gy - y0f;
        float wa = (1.0f - fx) * (1.0f - fy);
        float wb = (1.0f - fx) * fy;
        float wc = fx * (1.0f - fy);
        float wd = fx * fy;
        bool vx0 = (x0f >= 0.0f) && (x0f <= (float)(w - 1));
        bool vx1 = (x0f >= -1.0f) && (x0f <= (float)(w - 2));
        bool vy0 = (y0f >= 0.0f) && (y0f <= (float)(h - 1));
        bool vy1 = (y0f >= -1.0f) && (y0f <= (float)(h - 2));
        int xi0 = (int)fminf(fmaxf(x0f, 0.0f), (float)(w - 1));
        int xi1 = (int)fminf(fmaxf(x0f + 1.0f, 0.0f), (float)(w - 1));
        int yi0 = (int)fminf(fmaxf(y0f, 0.0f), (float)(h - 1));
        int yi1 = (int)fminf(fmaxf(y0f + 1.0f, 0.0f), (float)(h - 1));
        float waf = (vx0 && vy0) ? wa : 0.0f;
        float wbf = (vx0 && vy1) ? wb : 0.0f;
        float wcf = (vx1 && vy0) ? wc : 0.0f;
        float wdf = (vx1 && vy1) ? wd : 0.0f;

        const uint2* plane = tg + ((size_t)(n * 8 + b) << LP);
        uint2 ua = plane[(yi0 << LOG2W) + xi0];
        uint2 ub = plane[(yi1 << LOG2W) + xi0];
        uint2 uc = plane[(yi0 << LOG2W) + xi1];
        uint2 ud = plane[(yi1 << LOG2W) + xi1];
        float3 ta = unpack_px(ua), tb = unpack_px(ub), tc = unpack_px(uc), td = unpack_px(ud);

        float m = mask[((size_t)(b * 2 + n) << LP) + pix];
        float v0 = waf * ta.x + wbf * tb.x + wcf * tc.x + wdf * td.x;
        float v1 = waf * ta.y + wbf * tb.y + wcf * tc.y + wdf * td.y;
        float v2 = waf * ta.z + wbf * tb.z + wcf * tc.z + wdf * td.z;
        acc += m * (fabsf(rc[0] - v0) + fabsf(rc[1] - v1) + fabsf(rc[2] - v2));
    }
    return acc * inv_count;
}

__global__ __launch_bounds__(256) void photo_all_packed(
    const float* __restrict__ rrF,
    const uint2* __restrict__ rr1, const uint2* __restrict__ rr2, const uint2* __restrict__ rr3,
    const float* __restrict__ dep0, const float* __restrict__ msk0,
    const float* __restrict__ dep1, const float* __restrict__ msk1,
    const float* __restrict__ dep2, const float* __restrict__ msk2,
    const float* __restrict__ dep3, const float* __restrict__ msk3,
    const uint2* __restrict__ packF,
    const uint2* __restrict__ pL1t, const uint2* __restrict__ pL2t, const uint2* __restrict__ pL3t,
    const float* __restrict__ pose, float* __restrict__ out) {
    __shared__ float ldsRt[24];
    __shared__ float wsum[4];
    int bid = blockIdx.x, tid = threadIdx.x;
    float acc;
    if (bid < 16384)
        acc = photo_scale_packed<0>(bid, tid, rrF, nullptr, dep0, msk0, packF, pose, ldsRt);
    else if (bid < 20480)
        acc = photo_scale_packed<1>(bid - 16384, tid, nullptr, rr1, dep1, msk1, pL1t, pose, ldsRt);
    else if (bid < 21504)
        acc = photo_scale_packed<2>(bid - 20480, tid, nullptr, rr2, dep2, msk2, pL2t, pose, ldsRt);
    else
        acc = photo_scale_packed<3>(bid - 21504, tid, nullptr, rr3, dep3, msk3, pL3t, pose, ldsRt);

    for (int off = 32; off > 0; off >>= 1) acc += __shfl_down(acc, off);
    if ((tid & 63) == 0) wsum[tid >> 6] = acc;
    __syncthreads();
    if (tid == 0) atomicAdd(out, wsum[0] + wsum[1] + wsum[2] + wsum[3]);
}

// ================= fallback path (round-3 proven kernels) =================
template <int LWD>
__global__ __launch_bounds__(256) void down3_kernel(const float* __restrict__ sA,
                                                    const float* __restrict__ sB,
                                                    const float* __restrict__ sC,
                                                    float* __restrict__ dA,
                                                    float* __restrict__ dB,
                                                    float* __restrict__ dC) {
    const float* src = (blockIdx.y == 0) ? sA : (blockIdx.y == 1) ? sB : sC;
    float* dst = (blockIdx.y == 0) ? dA : (blockIdx.y == 1) ? dB : dC;
    int idx = blockIdx.x * 256 + threadIdx.x;
    constexpr int HB = LWD - 1;
    int xp = idx & ((1 << HB) - 1);
    int y = (idx >> HB) & ((1 << HB) - 1);
    int c = idx >> (2 * HB);
    const float* sp = src + ((size_t)c << (2 * LWD + 1)) + ((size_t)(2 * y) << (LWD + 1)) + 4 * xp;
    float4 r0 = *(const float4*)sp;
    float4 r1 = *(const float4*)(sp + (1 << (LWD + 1)));
    float2 d;
    d.x = 0.25f * (r0.x + r0.y + r1.x + r1.y);
    d.y = 0.25f * (r0.z + r0.w + r1.z + r1.w);
    *(float2*)(dst + ((size_t)c << (2 * LWD - 1)) + ((size_t)y << LWD) + 2 * xp) = d;
}

template <int SH>
__device__ inline float photo_scale(int bidl, int tid,
                                    const float* __restrict__ rr,
                                    const float* __restrict__ depth,
                                    const float* __restrict__ mask,
                                    const float* __restrict__ tg0,
                                    const float* __restrict__ tg1,
                                    const float* __restrict__ pose,
                                    float* __restrict__ ldsRt) {
    constexpr int h = 512 >> SH;
    constexpr int w = 1024 >> SH;
    constexpr int LOG2W = 10 - SH;
    constexpr int LP = 19 - 2 * SH;
    constexpr float inv_count = 1.0f / (8.0f * 3.0f * h * w);
    int lidx = (bidl << 8) + tid;
    int b = lidx >> LP;
    if (tid < 2) make_Rt_to(pose, b * 2 + tid, ldsRt + tid * 12);
    __syncthreads();
    int x = lidx & (w - 1);
    int y = (lidx >> LOG2W) & (h - 1);
    int pix = (y << LOG2W) + x;
    float lon = (((float)x + 0.5f) * (2.0f / (float)w) - 1.0f) * PI_F;
    float lat = -(((float)y + 0.5f) * (2.0f / (float)h) - 1.0f) * (0.5f * PI_F);
    float sl = __sinf(lon), cl = __cosf(lon);
    float slat = __sinf(lat), clat = __cosf(lat);
    float dep = depth[((size_t)b << LP) + pix];
    float X = dep * clat * sl, Y = dep * slat, Z = dep * clat * cl;
    float rc[3];
#pragma unroll
    for (int c = 0; c < 3; ++c)
        rc[c] = rr[((size_t)(b * 3 + c) << LP) + pix];
    float acc = 0.0f;
#pragma unroll
    for (int n = 0; n < 2; ++n) {
        const float* R = ldsRt + n * 12;
        float px = R[0] * X + R[1] * Y + R[2] * Z + R[9];
        float py = R[3] * X + R[4] * Y + R[5] * Z + R[10];
        float pz = R[6] * X + R[7] * Y + R[8] * Z + R[11];
        float rxz = sqrtf(px * px + pz * pz);
        float lon2 = fast_atan2f(px, pz);
        float lat2 = fast_atan2f(py, rxz);
        float gx = (lon2 * (1.0f / PI_F) + 1.0f) * 0.5f * (float)(w - 1);
        float gy = (lat2 * (2.0f / PI_F) + 1.0f) * 0.5f * (float)(h - 1);
        float x0f = floorf(gx), y0f = floorf(gy);
        float fx = gx - x0f, fy = gy - y0f;
        float wa = (1.0f - fx) * (1.0f - fy);
        float wb = (1.0f - fx) * fy;
        float wc = fx * (1.0f - fy);
        float wd = fx * fy;
        bool vx0 = (x0f >= 0.0f) && (x0f <= (float)(w - 1));
        bool vx1 = (x0f >= -1.0f) && (x0f <= (float)(w - 2));
        bool vy0 = (y0f >= 0.0f) && (y0f <= (float)(h - 1));
        bool vy1 = (y0f >= -1.0f) && (y0f <= (float)(h - 2));
        int xi0 = (int)fminf(fmaxf(x0f, 0.0f), (float)(w - 1));
        int xi1 = (int)fminf(fmaxf(x0f + 1.0f, 0.0f), (float)(w - 1));
        int yi0 = (int)fminf(fmaxf(y0f, 0.0f), (float)(h - 1));
        int yi1 = (int)fminf(fmaxf(y0f + 1.0f, 0.0f), (float)(h - 1));
        float waf = (vx0 && vy0) ? wa : 0.0f;
        float wbf = (vx0 && vy1) ? wb : 0.0f;
        float wcf = (vx1 && vy0) ? wc : 0.0f;
        float wdf = (vx1 && vy1) ? wd : 0.0f;
        int ia = (yi0 << LOG2W) + xi0;
        int ib2 = (yi1 << LOG2W) + xi0;
        int ic = (yi0 << LOG2W) + xi1;
        int id = (yi1 << LOG2W) + xi1;
        const float* tg = (n == 0) ? tg0 : tg1;
        float m = mask[((size_t)(b * 2 + n) << LP) + pix];
#pragma unroll
        for (int c = 0; c < 3; ++c) {
            const float* plane = tg + ((size_t)(b * 3 + c) << LP);
            float v = waf * plane[ia] + wbf * plane[ib2] + wcf * plane[ic] + wdf * plane[id];
            acc += m * fabsf(rc[c] - v);
        }
    }
    return acc * inv_count;
}

__global__ __launch_bounds__(256) void photo_all_kernel(
    const float* __restrict__ rr0, const float* __restrict__ dep0, const float* __restrict__ msk0,
    const float* __restrict__ tA0, const float* __restrict__ tB0,
    const float* __restrict__ rr1, const float* __restrict__ dep1, const float* __restrict__ msk1,
    const float* __restrict__ tA1, const float* __restrict__ tB1,
    const float* __restrict__ rr2, const float* __restrict__ dep2, const float* __restrict__ msk2,
    const float* __restrict__ tA2, const float* __restrict__ tB2,
    const float* __restrict__ rr3, const float* __restrict__ dep3, const float* __restrict__ msk3,
    const float* __restrict__ tA3, const float* __restrict__ tB3,
    const float* __restrict__ pose, float* __restrict__ out) {
    __shared__ float ldsRt[24];
    __shared__ float wsum[4];
    int bid = blockIdx.x, tid = threadIdx.x;
    float acc;
    if (bid < 16384)
        acc = photo_scale<0>(bid, tid, rr0, dep0, msk0, tA0, tB0, pose, ldsRt);
    else if (bid < 20480)
        acc = photo_scale<1>(bid - 16384, tid, rr1, dep1, msk1, tA1, tB1, pose, ldsRt);
    else if (bid < 21504)
        acc = photo_scale<2>(bid - 20480, tid, rr2, dep2, msk2, tA2, tB2, pose, ldsRt);
    else
        acc = photo_scale<3>(bid - 21504, tid, rr3, dep3, msk3, tA3, tB3, pose, ldsRt);
    for (int off = 32; off > 0; off >>= 1) acc += __shfl_down(acc, off);
    if ((tid & 63) == 0) wsum[tid >> 6] = acc;
    __syncthreads();
    if (tid == 0) atomicAdd(out, wsum[0] + wsum[1] + wsum[2] + wsum[3]);
}

extern "C" void kernel_launch(void* const* d_in, const int* in_sizes, int n_in,
                              void* d_out, int out_size, void* d_ws, size_t ws_size,
                              hipStream_t stream) {
    // dict order: ref_rgb, (ref_depth{i}, exp_mask{i}) i=0..3, tgt_rgb0, tgt_rgb1, pose
    const float* ref  = (const float*)d_in[0];
    const float* dep0 = (const float*)d_in[1];
    const float* msk0 = (const float*)d_in[2];
    const float* dep1 = (const float*)d_in[3];
    const float* msk1 = (const float*)d_in[4];
    const float* dep2 = (const float*)d_in[5];
    const float* msk2 = (const float*)d_in[6];
    const float* dep3 = (const float*)d_in[7];
    const float* msk3 = (const float*)d_in[8];
    const float* tgt0 = (const float*)d_in[9];
    const float* tgt1 = (const float*)d_in[10];
    const float* pose = (const float*)d_in[11];
    float* out = (float*)d_out;

    hipMemsetAsync(out, 0, sizeof(float), stream);

    // packed-path workspace (uint2 elements)
    const size_t E_F   = (size_t)16 << 19;
    const size_t E_L1t = (size_t)16 << 17;
    const size_t E_L2t = (size_t)16 << 15;
    const size_t E_L3t = (size_t)16 << 13;
    const size_t E_L1r = (size_t)8 << 17;
    const size_t E_L2r = (size_t)8 << 15;
    const size_t E_L3r = (size_t)8 << 13;
    const size_t NEED_PACKED = (E_F + E_L1t + E_L2t + E_L3t + E_L1r + E_L2r + E_L3r) * sizeof(uint2);

    const size_t L1 = (size_t)24 * 256 * 512;
    const size_t L2 = (size_t)24 * 128 * 256;
    const size_t L3 = (size_t)24 * 64 * 128;
    const size_t NEED_A = 3 * (L1 + L2 + L3) * sizeof(float);

    if (ws_size >= NEED_PACKED) {
        uint2* p = (uint2*)d_ws;
        uint2* packF = p; p += E_F;
        uint2* pL1t = p; p += E_L1t;
        uint2* pL2t = p; p += E_L2t;
        uint2* pL3t = p; p += E_L3t;
        uint2* pL1r = p; p += E_L1r;
        uint2* pL2r = p; p += E_L2r;
        uint2* pL3r = p; p += E_L3r;

        prep_kernel<<<12288, 256, 0, stream>>>(ref, tgt0, tgt1, packF,
                                               pL1t, pL2t, pL3t, pL1r, pL2r, pL3r);
        photo_all_packed<<<21760, 256, 0, stream>>>(
            ref, pL1r, pL2r, pL3r,
            dep0, msk0, dep1, msk1, dep2, msk2, dep3, msk3,
            packF, pL1t, pL2t, pL3t, pose, out);
    } else if (ws_size >= NEED_A) {
        float* p = (float*)d_ws;
        float* ref_l1 = p; p += L1;
        float* ref_l2 = p; p += L2;
        float* ref_l3 = p; p += L3;
        float* t0_l1 = p; p += L1;
        float* t0_l2 = p; p += L2;
        float* t0_l3 = p; p += L3;
        float* t1_l1 = p; p += L1;
        float* t1_l2 = p; p += L2;
        float* t1_l3 = p; p += L3;
        down3_kernel<9><<<dim3((24 << 16) / 256, 3), 256, 0, stream>>>(
            ref, tgt0, tgt1, ref_l1, t0_l1, t1_l1);
        down3_kernel<8><<<dim3((24 << 14) / 256, 3), 256, 0, stream>>>(
            ref_l1, t0_l1, t1_l1, ref_l2, t0_l2, t1_l2);
        down3_kernel<7><<<dim3((24 << 12) / 256, 3), 256, 0, stream>>>(
            ref_l2, t0_l2, t1_l2, ref_l3, t0_l3, t1_l3);
        photo_all_kernel<<<21760, 256, 0, stream>>>(
            ref, dep0, msk0, tgt0, tgt1,
            ref_l1, dep1, msk1, t0_l1, t1_l1,
            ref_l2, dep2, msk2, t0_l2, t1_l2,
            ref_l3, dep3, msk3, t0_l3, t1_l3,
            pose, out);
    }
}

// Round 5
// 357.623 us; speedup vs baseline: 1.4178x; 1.4178x over previous
//
#include <hip/hip_runtime.h>
#include <hip/hip_fp16.h>
#include <math.h>

#define PI_F 3.14159265358979323846f

// ---------------- fast atan2 (minimax deg-11, max err ~1e-5 rad) ----------------
__device__ inline float fast_atan2f(float y, float x) {
    float ax = fabsf(x), ay = fabsf(y);
    float mx = fmaxf(ax, ay);
    float mn = fminf(ax, ay);
    float a = __fdividef(mn, fmaxf(mx, 1e-30f));
    float s = a * a;
    float r = fmaf(s, fmaf(s, fmaf(s, fmaf(s, fmaf(s, -0.01172120f, 0.05265332f),
                   -0.11643287f), 0.19354346f), -0.33262347f), 0.99997726f);
    r = r * a;
    if (ay > ax) r = 1.57079632679f - r;
    if (x < 0.0f) r = PI_F - r;
    return copysignf(r, y);
}

// Rodrigues: pose (tx,ty,tz,rx,ry,rz) -> o[0..8]=R row-major, o[9..11]=t
__device__ inline void make_Rt_to(const float* __restrict__ pose, int bn, float* __restrict__ o) {
    const float* p = pose + bn * 6;
    float tx = p[0], ty = p[1], tz = p[2];
    float rx = p[3], ry = p[4], rz = p[5];
    float theta = sqrtf(rx * rx + ry * ry + rz * rz);
    float inv = __fdividef(1.0f, fmaxf(theta, 1e-8f));
    float kx = rx * inv, ky = ry * inv, kz = rz * inv;
    float s, c;
    __sincosf(theta, &s, &c);
    float oc = 1.0f - c;
    o[0] = 1.0f - oc * (ky * ky + kz * kz);
    o[1] = -s * kz + oc * kx * ky;
    o[2] =  s * ky + oc * kx * kz;
    o[3] =  s * kz + oc * kx * ky;
    o[4] = 1.0f - oc * (kx * kx + kz * kz);
    o[5] = -s * kx + oc * ky * kz;
    o[6] = -s * ky + oc * kx * kz;
    o[7] =  s * kx + oc * ky * kz;
    o[8] = 1.0f - oc * (kx * kx + ky * ky);
    o[9] = tx; o[10] = ty; o[11] = tz;
}

// ---------------- fp16 RGBx packing (8 B / pixel) ----------------
__device__ inline uint2 pack_px(float r, float g, float b) {
    __half2 a = __floats2half2_rn(r, g);
    __half2 c = __floats2half2_rn(b, 0.0f);
    uint2 u;
    u.x = *(const unsigned int*)&a;
    u.y = *(const unsigned int*)&c;
    return u;
}
__device__ inline float3 unpack_px(uint2 u) {
    __half2 a = *(const __half2*)&u.x;
    __half2 c = *(const __half2*)&u.y;
    float2 f = __half22float2(a);
    return make_float3(f.x, f.y, __low2float(c));
}

// ---------------- prep: streaming row-band pass --------------------------------
// block = one 8-row band of one (i,b) plane. lanes cover the full 1024-px row.
// Builds: packed full-res tgt, packed L1/L2/L3 for tgt and ref.
__global__ __launch_bounds__(256) void prep_kernel(
    const float* __restrict__ ref, const float* __restrict__ tgt0, const float* __restrict__ tgt1,
    uint2* __restrict__ packF,
    uint2* __restrict__ pL1t, uint2* __restrict__ pL2t, uint2* __restrict__ pL3t,
    uint2* __restrict__ pL1r, uint2* __restrict__ pL2r, uint2* __restrict__ pL3r)
{
    int bid = blockIdx.x;          // 24 * 64
    int band = bid & 63;
    int ib = bid >> 6;             // 0..23
    int b = ib & 7;
    int i = ib >> 3;               // 0=ref 1=tgt0 2=tgt1
    const float* img = (i == 0) ? ref : (i == 1) ? tgt0 : tgt1;
    int t = threadIdx.x;
    int x4 = t << 2;
    int y0 = band << 3;
    int q = (i - 1) * 8 + b;

    float l1v[4][2][3];            // [rowpair][xpair][ch]
#pragma unroll
    for (int p = 0; p < 4; ++p) {
        float4 a[3], bb[3];
#pragma unroll
        for (int c = 0; c < 3; ++c) {
            const float* pl = img + ((size_t)(b * 3 + c) << 19);
            a[c]  = *(const float4*)(pl + ((y0 + 2 * p) << 10) + x4);
            bb[c] = *(const float4*)(pl + ((y0 + 2 * p + 1) << 10) + x4);
        }
        if (i > 0) {
            uint2* o = packF + ((size_t)q << 19) + ((y0 + 2 * p) << 10) + x4;
            uint2 p0 = pack_px(a[0].x, a[1].x, a[2].x);
            uint2 p1 = pack_px(a[0].y, a[1].y, a[2].y);
            uint2 p2 = pack_px(a[0].z, a[1].z, a[2].z);
            uint2 p3 = pack_px(a[0].w, a[1].w, a[2].w);
            uint4 v0; v0.x = p0.x; v0.y = p0.y; v0.z = p1.x; v0.w = p1.y;
            uint4 v1; v1.x = p2.x; v1.y = p2.y; v1.z = p3.x; v1.w = p3.y;
            *(uint4*)o = v0;
            *(uint4*)(o + 2) = v1;
            uint2* o2 = o + (1 << 10);
            p0 = pack_px(bb[0].x, bb[1].x, bb[2].x);
            p1 = pack_px(bb[0].y, bb[1].y, bb[2].y);
            p2 = pack_px(bb[0].z, bb[1].z, bb[2].z);
            p3 = pack_px(bb[0].w, bb[1].w, bb[2].w);
            v0.x = p0.x; v0.y = p0.y; v0.z = p1.x; v0.w = p1.y;
            v1.x = p2.x; v1.y = p2.y; v1.z = p3.x; v1.w = p3.y;
            *(uint4*)o2 = v0;
            *(uint4*)(o2 + 2) = v1;
        }
#pragma unroll
        for (int c = 0; c < 3; ++c) {
            l1v[p][0][c] = (a[c].x + a[c].y + bb[c].x + bb[c].y) * 0.25f;
            l1v[p][1][c] = (a[c].z + a[c].w + bb[c].z + bb[c].w) * 0.25f;
        }
        // L1 store: row band*4+p, cols 2t, 2t+1 (512-wide)
        uint2 q0 = pack_px(l1v[p][0][0], l1v[p][0][1], l1v[p][0][2]);
        uint2 q1 = pack_px(l1v[p][1][0], l1v[p][1][1], l1v[p][1][2]);
        uint4 v; v.x = q0.x; v.y = q0.y; v.z = q1.x; v.w = q1.y;
        uint2* d1 = ((i == 0) ? pL1r + ((size_t)b << 17) : pL1t + ((size_t)q << 17))
                    + (((band << 2) + p) << 9) + (t << 1);
        *(uint4*)d1 = v;
    }
    // L2: rows band*2+pr (256-wide), col t
    float l2v[2][3];
#pragma unroll
    for (int pr = 0; pr < 2; ++pr) {
#pragma unroll
        for (int c = 0; c < 3; ++c)
            l2v[pr][c] = (l1v[2 * pr][0][c] + l1v[2 * pr][1][c] +
                          l1v[2 * pr + 1][0][c] + l1v[2 * pr + 1][1][c]) * 0.25f;
        uint2* d2 = ((i == 0) ? pL2r + ((size_t)b << 15) : pL2t + ((size_t)q << 15))
                    + (((band << 1) + pr) << 8) + t;
        *d2 = pack_px(l2v[pr][0], l2v[pr][1], l2v[pr][2]);
    }
    // L3: row band (128-wide), col t>>1
    float l3[3];
#pragma unroll
    for (int c = 0; c < 3; ++c) {
        float s = l2v[0][c] + l2v[1][c];
        l3[c] = (s + __shfl_xor(s, 1)) * 0.25f;
    }
    if ((t & 1) == 0) {
        uint2* d3 = ((i == 0) ? pL3r + ((size_t)b << 13) : pL3t + ((size_t)q << 13))
                    + (band << 7) + (t >> 1);
        *d3 = pack_px(l3[0], l3[1], l3[2]);
    }
}

// ---------------- packed photometric body, 4 px per thread ----------------
template <int SH>
__device__ inline float photo_scale4(int bidl, int tid,
                                     const float* __restrict__ rrF,   // SH==0
                                     const uint2* __restrict__ rrP,   // SH>0
                                     const float* __restrict__ depth,
                                     const float* __restrict__ mask,
                                     const uint2* __restrict__ tg,    // planes q=n*8+b
                                     const float* __restrict__ pose,
                                     float* __restrict__ ldsRt) {
    constexpr int h = 512 >> SH;
    constexpr int w = 1024 >> SH;
    constexpr int LOG2W = 10 - SH;
    constexpr int LP = 19 - 2 * SH;
    constexpr float inv_count = 1.0f / (8.0f * 3.0f * h * w);

    int lidx = ((bidl << 8) + tid) << 2;
    int b = lidx >> LP;  // block-uniform
    if (tid < 2) make_Rt_to(pose, b * 2 + tid, ldsRt + tid * 12);
    __syncthreads();

    int x0 = lidx & (w - 1);
    int y = (lidx >> LOG2W) & (h - 1);
    int pix = (y << LOG2W) + x0;

    // shared across the 4 px (same row)
    float lat = -(((float)y + 0.5f) * (2.0f / (float)h) - 1.0f) * (0.5f * PI_F);
    float slat = __sinf(lat), clat = __cosf(lat);

    // vector loads: depth, ref, masks
    float4 dep4 = *(const float4*)(depth + ((size_t)b << LP) + pix);
    float dp[4] = {dep4.x, dep4.y, dep4.z, dep4.w};
    float rcv[4][3];
    if constexpr (SH == 0) {
#pragma unroll
        for (int c = 0; c < 3; ++c) {
            float4 rv = *(const float4*)(rrF + ((size_t)(b * 3 + c) << LP) + pix);
            rcv[0][c] = rv.x; rcv[1][c] = rv.y; rcv[2][c] = rv.z; rcv[3][c] = rv.w;
        }
    } else {
        const uint2* rp = rrP + ((size_t)b << LP) + pix;
        uint4 u01 = *(const uint4*)rp;
        uint4 u23 = *(const uint4*)(rp + 2);
        uint2 e0; e0.x = u01.x; e0.y = u01.y;
        uint2 e1; e1.x = u01.z; e1.y = u01.w;
        uint2 e2; e2.x = u23.x; e2.y = u23.y;
        uint2 e3; e3.x = u23.z; e3.y = u23.w;
        float3 f0 = unpack_px(e0), f1 = unpack_px(e1), f2 = unpack_px(e2), f3 = unpack_px(e3);
        rcv[0][0] = f0.x; rcv[0][1] = f0.y; rcv[0][2] = f0.z;
        rcv[1][0] = f1.x; rcv[1][1] = f1.y; rcv[1][2] = f1.z;
        rcv[2][0] = f2.x; rcv[2][1] = f2.y; rcv[2][2] = f2.z;
        rcv[3][0] = f3.x; rcv[3][1] = f3.y; rcv[3][2] = f3.z;
    }
    float m4[2][4];
#pragma unroll
    for (int n = 0; n < 2; ++n) {
        float4 mv = *(const float4*)(mask + ((size_t)(b * 2 + n) << LP) + pix);
        m4[n][0] = mv.x; m4[n][1] = mv.y; m4[n][2] = mv.z; m4[n][3] = mv.w;
    }

    float acc = 0.0f;
#pragma unroll
    for (int i = 0; i < 4; ++i) {
        float lon = (((float)(x0 + i) + 0.5f) * (2.0f / (float)w) - 1.0f) * PI_F;
        float sl = __sinf(lon), cl = __cosf(lon);
        float X = dp[i] * clat * sl, Y = dp[i] * slat, Z = dp[i] * clat * cl;
#pragma unroll
        for (int n = 0; n < 2; ++n) {
            const float* R = ldsRt + n * 12;
            float px = R[0] * X + R[1] * Y + R[2] * Z + R[9];
            float py = R[3] * X + R[4] * Y + R[5] * Z + R[10];
            float pz = R[6] * X + R[7] * Y + R[8] * Z + R[11];
            float rxz = sqrtf(px * px + pz * pz);
            float lon2 = fast_atan2f(px, pz);
            float lat2 = fast_atan2f(py, rxz);   // == asin(clip(py/norm))
            float gx = (lon2 * (1.0f / PI_F) + 1.0f) * 0.5f * (float)(w - 1);
            float gy = (lat2 * (2.0f / PI_F) + 1.0f) * 0.5f * (float)(h - 1);
            float x0f = floorf(gx), y0f = floorf(gy);
            float fx = gx - x0f, fy = gy - y0f;
            float wa = (1.0f - fx) * (1.0f - fy);
            float wb = (1.0f - fx) * fy;
            float wc = fx * (1.0f - fy);
            float wd = fx * fy;
            bool vx0 = (x0f >= 0.0f) && (x0f <= (float)(w - 1));
            bool vx1 = (x0f >= -1.0f) && (x0f <= (float)(w - 2));
            bool vy0 = (y0f >= 0.0f) && (y0f <= (float)(h - 1));
            bool vy1 = (y0f >= -1.0f) && (y0f <= (float)(h - 2));
            int xi0 = (int)fminf(fmaxf(x0f, 0.0f), (float)(w - 1));
            int xi1 = (int)fminf(fmaxf(x0f + 1.0f, 0.0f), (float)(w - 1));
            int yi0 = (int)fminf(fmaxf(y0f, 0.0f), (float)(h - 1));
            int yi1 = (int)fminf(fmaxf(y0f + 1.0f, 0.0f), (float)(h - 1));
            float waf = (vx0 && vy0) ? wa : 0.0f;
            float wbf = (vx0 && vy1) ? wb : 0.0f;
            float wcf = (vx1 && vy0) ? wc : 0.0f;
            float wdf = (vx1 && vy1) ? wd : 0.0f;

            const uint2* plane = tg + ((size_t)(n * 8 + b) << LP);
            uint2 ua = plane[(yi0 << LOG2W) + xi0];
            uint2 ub = plane[(yi1 << LOG2W) + xi0];
            uint2 uc = plane[(yi0 << LOG2W) + xi1];
            uint2 ud = plane[(yi1 << LOG2W) + xi1];
            float3 ta = unpack_px(ua), tb = unpack_px(ub), tc = unpack_px(uc), td = unpack_px(ud);

            float m = m4[n][i];
            float v0 = waf * ta.x + wbf * tb.x + wcf * tc.x + wdf * td.x;
            float v1 = waf * ta.y + wbf * tb.y + wcf * tc.y + wdf * td.y;
            float v2 = waf * ta.z + wbf * tb.z + wcf * tc.z + wdf * td.z;
            acc += m * (fabsf(rcv[i][0] - v0) + fabsf(rcv[i][1] - v1) + fabsf(rcv[i][2] - v2));
        }
    }
    return acc * inv_count;
}

__global__ __launch_bounds__(256) void photo_all_packed4(
    const float* __restrict__ rrF,
    const uint2* __restrict__ rr1, const uint2* __restrict__ rr2, const uint2* __restrict__ rr3,
    const float* __restrict__ dep0, const float* __restrict__ msk0,
    const float* __restrict__ dep1, const float* __restrict__ msk1,
    const float* __restrict__ dep2, const float* __restrict__ msk2,
    const float* __restrict__ dep3, const float* __restrict__ msk3,
    const uint2* __restrict__ packF,
    const uint2* __restrict__ pL1t, const uint2* __restrict__ pL2t, const uint2* __restrict__ pL3t,
    const float* __restrict__ pose, float* __restrict__ out) {
    __shared__ float ldsRt[24];
    __shared__ float wsum[4];
    int bid = blockIdx.x, tid = threadIdx.x;
    float acc;
    if (bid < 4096)
        acc = photo_scale4<0>(bid, tid, rrF, nullptr, dep0, msk0, packF, pose, ldsRt);
    else if (bid < 5120)
        acc = photo_scale4<1>(bid - 4096, tid, nullptr, rr1, dep1, msk1, pL1t, pose, ldsRt);
    else if (bid < 5376)
        acc = photo_scale4<2>(bid - 5120, tid, nullptr, rr2, dep2, msk2, pL2t, pose, ldsRt);
    else
        acc = photo_scale4<3>(bid - 5376, tid, nullptr, rr3, dep3, msk3, pL3t, pose, ldsRt);

    for (int off = 32; off > 0; off >>= 1) acc += __shfl_down(acc, off);
    if ((tid & 63) == 0) wsum[tid >> 6] = acc;
    __syncthreads();
    if (tid == 0) atomicAdd(out, wsum[0] + wsum[1] + wsum[2] + wsum[3]);
}

// ================= fallback path (round-3 proven fp32 kernels) =================
template <int LWD>
__global__ __launch_bounds__(256) void down3_kernel(const float* __restrict__ sA,
                                                    const float* __restrict__ sB,
                                                    const float* __restrict__ sC,
                                                    float* __restrict__ dA,
                                                    float* __restrict__ dB,
                                                    float* __restrict__ dC) {
    const float* src = (blockIdx.y == 0) ? sA : (blockIdx.y == 1) ? sB : sC;
    float* dst = (blockIdx.y == 0) ? dA : (blockIdx.y == 1) ? dB : dC;
    int idx = blockIdx.x * 256 + threadIdx.x;
    constexpr int HB = LWD - 1;
    int xp = idx & ((1 << HB) - 1);
    int y = (idx >> HB) & ((1 << HB) - 1);
    int c = idx >> (2 * HB);
    const float* sp = src + ((size_t)c << (2 * LWD + 1)) + ((size_t)(2 * y) << (LWD + 1)) + 4 * xp;
    float4 r0 = *(const float4*)sp;
    float4 r1 = *(const float4*)(sp + (1 << (LWD + 1)));
    float2 d;
    d.x = 0.25f * (r0.x + r0.y + r1.x + r1.y);
    d.y = 0.25f * (r0.z + r0.w + r1.z + r1.w);
    *(float2*)(dst + ((size_t)c << (2 * LWD - 1)) + ((size_t)y << LWD) + 2 * xp) = d;
}

template <int SH>
__device__ inline float photo_scale(int bidl, int tid,
                                    const float* __restrict__ rr,
                                    const float* __restrict__ depth,
                                    const float* __restrict__ mask,
                                    const float* __restrict__ tg0,
                                    const float* __restrict__ tg1,
                                    const float* __restrict__ pose,
                                    float* __restrict__ ldsRt) {
    constexpr int h = 512 >> SH;
    constexpr int w = 1024 >> SH;
    constexpr int LOG2W = 10 - SH;
    constexpr int LP = 19 - 2 * SH;
    constexpr float inv_count = 1.0f / (8.0f * 3.0f * h * w);
    int lidx = (bidl << 8) + tid;
    int b = lidx >> LP;
    if (tid < 2) make_Rt_to(pose, b * 2 + tid, ldsRt + tid * 12);
    __syncthreads();
    int x = lidx & (w - 1);
    int y = (lidx >> LOG2W) & (h - 1);
    int pix = (y << LOG2W) + x;
    float lon = (((float)x + 0.5f) * (2.0f / (float)w) - 1.0f) * PI_F;
    float lat = -(((float)y + 0.5f) * (2.0f / (float)h) - 1.0f) * (0.5f * PI_F);
    float sl = __sinf(lon), cl = __cosf(lon);
    float slat = __sinf(lat), clat = __cosf(lat);
    float dep = depth[((size_t)b << LP) + pix];
    float X = dep * clat * sl, Y = dep * slat, Z = dep * clat * cl;
    float rc[3];
#pragma unroll
    for (int c = 0; c < 3; ++c)
        rc[c] = rr[((size_t)(b * 3 + c) << LP) + pix];
    float acc = 0.0f;
#pragma unroll
    for (int n = 0; n < 2; ++n) {
        const float* R = ldsRt + n * 12;
        float px = R[0] * X + R[1] * Y + R[2] * Z + R[9];
        float py = R[3] * X + R[4] * Y + R[5] * Z + R[10];
        float pz = R[6] * X + R[7] * Y + R[8] * Z + R[11];
        float rxz = sqrtf(px * px + pz * pz);
        float lon2 = fast_atan2f(px, pz);
        float lat2 = fast_atan2f(py, rxz);
        float gx = (lon2 * (1.0f / PI_F) + 1.0f) * 0.5f * (float)(w - 1);
        float gy = (lat2 * (2.0f / PI_F) + 1.0f) * 0.5f * (float)(h - 1);
        float x0f = floorf(gx), y0f = floorf(gy);
        float fx = gx - x0f, fy = gy - y0f;
        float wa = (1.0f - fx) * (1.0f - fy);
        float wb = (1.0f - fx) * fy;
        float wc = fx * (1.0f - fy);
        float wd = fx * fy;
        bool vx0 = (x0f >= 0.0f) && (x0f <= (float)(w - 1));
        bool vx1 = (x0f >= -1.0f) && (x0f <= (float)(w - 2));
        bool vy0 = (y0f >= 0.0f) && (y0f <= (float)(h - 1));
        bool vy1 = (y0f >= -1.0f) && (y0f <= (float)(h - 2));
        int xi0 = (int)fminf(fmaxf(x0f, 0.0f), (float)(w - 1));
        int xi1 = (int)fminf(fmaxf(x0f + 1.0f, 0.0f), (float)(w - 1));
        int yi0 = (int)fminf(fmaxf(y0f, 0.0f), (float)(h - 1));
        int yi1 = (int)fminf(fmaxf(y0f + 1.0f, 0.0f), (float)(h - 1));
        float waf = (vx0 && vy0) ? wa : 0.0f;
        float wbf = (vx0 && vy1) ? wb : 0.0f;
        float wcf = (vx1 && vy0) ? wc : 0.0f;
        float wdf = (vx1 && vy1) ? wd : 0.0f;
        int ia = (yi0 << LOG2W) + xi0;
        int ib2 = (yi1 << LOG2W) + xi0;
        int ic = (yi0 << LOG2W) + xi1;
        int id = (yi1 << LOG2W) + xi1;
        const float* tg = (n == 0) ? tg0 : tg1;
        float m = mask[((size_t)(b * 2 + n) << LP) + pix];
#pragma unroll
        for (int c = 0; c < 3; ++c) {
            const float* plane = tg + ((size_t)(b * 3 + c) << LP);
            float v = waf * plane[ia] + wbf * plane[ib2] + wcf * plane[ic] + wdf * plane[id];
            acc += m * fabsf(rc[c] - v);
        }
    }
    return acc * inv_count;
}

__global__ __launch_bounds__(256) void photo_all_kernel(
    const float* __restrict__ rr0, const float* __restrict__ dep0, const float* __restrict__ msk0,
    const float* __restrict__ tA0, const float* __restrict__ tB0,
    const float* __restrict__ rr1, const float* __restrict__ dep1, const float* __restrict__ msk1,
    const float* __restrict__ tA1, const float* __restrict__ tB1,
    const float* __restrict__ rr2, const float* __restrict__ dep2, const float* __restrict__ msk2,
    const float* __restrict__ tA2, const float* __restrict__ tB2,
    const float* __restrict__ rr3, const float* __restrict__ dep3, const float* __restrict__ msk3,
    const float* __restrict__ tA3, const float* __restrict__ tB3,
    const float* __restrict__ pose, float* __restrict__ out) {
    __shared__ float ldsRt[24];
    __shared__ float wsum[4];
    int bid = blockIdx.x, tid = threadIdx.x;
    float acc;
    if (bid < 16384)
        acc = photo_scale<0>(bid, tid, rr0, dep0, msk0, tA0, tB0, pose, ldsRt);
    else if (bid < 20480)
        acc = photo_scale<1>(bid - 16384, tid, rr1, dep1, msk1, tA1, tB1, pose, ldsRt);
    else if (bid < 21504)
        acc = photo_scale<2>(bid - 20480, tid, rr2, dep2, msk2, tA2, tB2, pose, ldsRt);
    else
        acc = photo_scale<3>(bid - 21504, tid, rr3, dep3, msk3, tA3, tB3, pose, ldsRt);
    for (int off = 32; off > 0; off >>= 1) acc += __shfl_down(acc, off);
    if ((tid & 63) == 0) wsum[tid >> 6] = acc;
    __syncthreads();
    if (tid == 0) atomicAdd(out, wsum[0] + wsum[1] + wsum[2] + wsum[3]);
}

extern "C" void kernel_launch(void* const* d_in, const int* in_sizes, int n_in,
                              void* d_out, int out_size, void* d_ws, size_t ws_size,
                              hipStream_t stream) {
    // dict order: ref_rgb, (ref_depth{i}, exp_mask{i}) i=0..3, tgt_rgb0, tgt_rgb1, pose
    const float* ref  = (const float*)d_in[0];
    const float* dep0 = (const float*)d_in[1];
    const float* msk0 = (const float*)d_in[2];
    const float* dep1 = (const float*)d_in[3];
    const float* msk1 = (const float*)d_in[4];
    const float* dep2 = (const float*)d_in[5];
    const float* msk2 = (const float*)d_in[6];
    const float* dep3 = (const float*)d_in[7];
    const float* msk3 = (const float*)d_in[8];
    const float* tgt0 = (const float*)d_in[9];
    const float* tgt1 = (const float*)d_in[10];
    const float* pose = (const float*)d_in[11];
    float* out = (float*)d_out;

    hipMemsetAsync(out, 0, sizeof(float), stream);

    const size_t E_F   = (size_t)16 << 19;
    const size_t E_L1t = (size_t)16 << 17;
    const size_t E_L2t = (size_t)16 << 15;
    const size_t E_L3t = (size_t)16 << 13;
    const size_t E_L1r = (size_t)8 << 17;
    const size_t E_L2r = (size_t)8 << 15;
    const size_t E_L3r = (size_t)8 << 13;
    const size_t NEED_PACKED = (E_F + E_L1t + E_L2t + E_L3t + E_L1r + E_L2r + E_L3r) * sizeof(uint2);

    const size_t L1 = (size_t)24 * 256 * 512;
    const size_t L2 = (size_t)24 * 128 * 256;
    const size_t L3 = (size_t)24 * 64 * 128;
    const size_t NEED_A = 3 * (L1 + L2 + L3) * sizeof(float);

    if (ws_size >= NEED_PACKED) {
        uint2* p = (uint2*)d_ws;
        uint2* packF = p; p += E_F;
        uint2* pL1t = p; p += E_L1t;
        uint2* pL2t = p; p += E_L2t;
        uint2* pL3t = p; p += E_L3t;
        uint2* pL1r = p; p += E_L1r;
        uint2* pL2r = p; p += E_L2r;
        uint2* pL3r = p; p += E_L3r;

        prep_kernel<<<1536, 256, 0, stream>>>(ref, tgt0, tgt1, packF,
                                              pL1t, pL2t, pL3t, pL1r, pL2r, pL3r);
        photo_all_packed4<<<5440, 256, 0, stream>>>(
            ref, pL1r, pL2r, pL3r,
            dep0, msk0, dep1, msk1, dep2, msk2, dep3, msk3,
            packF, pL1t, pL2t, pL3t, pose, out);
    } else if (ws_size >= NEED_A) {
        float* p = (float*)d_ws;
        float* ref_l1 = p; p += L1;
        float* ref_l2 = p; p += L2;
        float* ref_l3 = p; p += L3;
        float* t0_l1 = p; p += L1;
        float* t0_l2 = p; p += L2;
        float* t0_l3 = p; p += L3;
        float* t1_l1 = p; p += L1;
        float* t1_l2 = p; p += L2;
        float* t1_l3 = p; p += L3;
        down3_kernel<9><<<dim3((24 << 16) / 256, 3), 256, 0, stream>>>(
            ref, tgt0, tgt1, ref_l1, t0_l1, t1_l1);
        down3_kernel<8><<<dim3((24 << 14) / 256, 3), 256, 0, stream>>>(
            ref_l1, t0_l1, t1_l1, ref_l2, t0_l2, t1_l2);
        down3_kernel<7><<<dim3((24 << 12) / 256, 3), 256, 0, stream>>>(
            ref_l2, t0_l2, t1_l2, ref_l3, t0_l3, t1_l3);
        photo_all_kernel<<<21760, 256, 0, stream>>>(
            ref, dep0, msk0, tgt0, tgt1,
            ref_l1, dep1, msk1, t0_l1, t1_l1,
            ref_l2, dep2, msk2, t0_l2, t1_l2,
            ref_l3, dep3, msk3, t0_l3, t1_l3,
            pose, out);
    }
}

// Round 6
// 349.574 us; speedup vs baseline: 1.4505x; 1.0230x over previous
//
#include <hip/hip_runtime.h>
#include <hip/hip_fp16.h>
#include <math.h>

#define PI_F 3.14159265358979323846f

// ---------------- fast atan2 (minimax deg-11, max err ~1e-5 rad) ----------------
__device__ inline float fast_atan2f(float y, float x) {
    float ax = fabsf(x), ay = fabsf(y);
    float mx = fmaxf(ax, ay);
    float mn = fminf(ax, ay);
    float a = __fdividef(mn, fmaxf(mx, 1e-30f));
    float s = a * a;
    float r = fmaf(s, fmaf(s, fmaf(s, fmaf(s, fmaf(s, -0.01172120f, 0.05265332f),
                   -0.11643287f), 0.19354346f), -0.33262347f), 0.99997726f);
    r = r * a;
    if (ay > ax) r = 1.57079632679f - r;
    if (x < 0.0f) r = PI_F - r;
    return copysignf(r, y);
}

// Rodrigues: pose (tx,ty,tz,rx,ry,rz) -> o[0..8]=R row-major, o[9..11]=t
__device__ inline void make_Rt_to(const float* __restrict__ pose, int bn, float* __restrict__ o) {
    const float* p = pose + bn * 6;
    float tx = p[0], ty = p[1], tz = p[2];
    float rx = p[3], ry = p[4], rz = p[5];
    float theta = sqrtf(rx * rx + ry * ry + rz * rz);
    float inv = __fdividef(1.0f, fmaxf(theta, 1e-8f));
    float kx = rx * inv, ky = ry * inv, kz = rz * inv;
    float s, c;
    __sincosf(theta, &s, &c);
    float oc = 1.0f - c;
    o[0] = 1.0f - oc * (ky * ky + kz * kz);
    o[1] = -s * kz + oc * kx * ky;
    o[2] =  s * ky + oc * kx * kz;
    o[3] =  s * kz + oc * kx * ky;
    o[4] = 1.0f - oc * (kx * kx + kz * kz);
    o[5] = -s * kx + oc * ky * kz;
    o[6] = -s * ky + oc * kx * kz;
    o[7] =  s * kx + oc * ky * kz;
    o[8] = 1.0f - oc * (kx * kx + ky * ky);
    o[9] = tx; o[10] = ty; o[11] = tz;
}

// ---------------- fp16 RGBx packing (8 B / pixel) ----------------
__device__ inline uint2 pack_px(float r, float g, float b) {
    __half2 a = __floats2half2_rn(r, g);
    __half2 c = __floats2half2_rn(b, 0.0f);
    uint2 u;
    u.x = *(const unsigned int*)&a;
    u.y = *(const unsigned int*)&c;
    return u;
}
__device__ inline float3 unpack_px(uint2 u) {
    __half2 a = *(const __half2*)&u.x;
    __half2 c = *(const __half2*)&u.y;
    float2 f = __half22float2(a);
    return make_float3(f.x, f.y, __low2float(c));
}

// ---------------- prep: streaming row-band pass (also zeroes out[0]) -----------
__global__ __launch_bounds__(256) void prep_kernel(
    const float* __restrict__ ref, const float* __restrict__ tgt0, const float* __restrict__ tgt1,
    uint2* __restrict__ packF,
    uint2* __restrict__ pL1t, uint2* __restrict__ pL2t, uint2* __restrict__ pL3t,
    uint2* __restrict__ pL1r, uint2* __restrict__ pL2r, uint2* __restrict__ pL3r,
    float* __restrict__ out)
{
    int bid = blockIdx.x;          // 24 * 64; i fastest for CU load mixing
    int t = threadIdx.x;
    if (bid == 0 && t == 0) out[0] = 0.0f;
    int i = bid % 3;               // 0=ref 1=tgt0 2=tgt1
    int rem = bid / 3;
    int b = rem & 7;
    int band = rem >> 3;           // 0..63
    const float* img = (i == 0) ? ref : (i == 1) ? tgt0 : tgt1;
    int x4 = t << 2;
    int y0 = band << 3;
    int q = (i - 1) * 8 + b;

    float l1v[4][2][3];            // [rowpair][xpair][ch]
#pragma unroll
    for (int p = 0; p < 4; ++p) {
        float4 a[3], bb[3];
#pragma unroll
        for (int c = 0; c < 3; ++c) {
            const float* pl = img + ((size_t)(b * 3 + c) << 19);
            a[c]  = *(const float4*)(pl + ((y0 + 2 * p) << 10) + x4);
            bb[c] = *(const float4*)(pl + ((y0 + 2 * p + 1) << 10) + x4);
        }
        if (i > 0) {
            uint2* o = packF + ((size_t)q << 19) + ((y0 + 2 * p) << 10) + x4;
            uint2 p0 = pack_px(a[0].x, a[1].x, a[2].x);
            uint2 p1 = pack_px(a[0].y, a[1].y, a[2].y);
            uint2 p2 = pack_px(a[0].z, a[1].z, a[2].z);
            uint2 p3 = pack_px(a[0].w, a[1].w, a[2].w);
            uint4 v0; v0.x = p0.x; v0.y = p0.y; v0.z = p1.x; v0.w = p1.y;
            uint4 v1; v1.x = p2.x; v1.y = p2.y; v1.z = p3.x; v1.w = p3.y;
            *(uint4*)o = v0;
            *(uint4*)(o + 2) = v1;
            uint2* o2 = o + (1 << 10);
            p0 = pack_px(bb[0].x, bb[1].x, bb[2].x);
            p1 = pack_px(bb[0].y, bb[1].y, bb[2].y);
            p2 = pack_px(bb[0].z, bb[1].z, bb[2].z);
            p3 = pack_px(bb[0].w, bb[1].w, bb[2].w);
            v0.x = p0.x; v0.y = p0.y; v0.z = p1.x; v0.w = p1.y;
            v1.x = p2.x; v1.y = p2.y; v1.z = p3.x; v1.w = p3.y;
            *(uint4*)o2 = v0;
            *(uint4*)(o2 + 2) = v1;
        }
#pragma unroll
        for (int c = 0; c < 3; ++c) {
            l1v[p][0][c] = (a[c].x + a[c].y + bb[c].x + bb[c].y) * 0.25f;
            l1v[p][1][c] = (a[c].z + a[c].w + bb[c].z + bb[c].w) * 0.25f;
        }
        uint2 q0 = pack_px(l1v[p][0][0], l1v[p][0][1], l1v[p][0][2]);
        uint2 q1 = pack_px(l1v[p][1][0], l1v[p][1][1], l1v[p][1][2]);
        uint4 v; v.x = q0.x; v.y = q0.y; v.z = q1.x; v.w = q1.y;
        uint2* d1 = ((i == 0) ? pL1r + ((size_t)b << 17) : pL1t + ((size_t)q << 17))
                    + (((band << 2) + p) << 9) + (t << 1);
        *(uint4*)d1 = v;
    }
    float l2v[2][3];
#pragma unroll
    for (int pr = 0; pr < 2; ++pr) {
#pragma unroll
        for (int c = 0; c < 3; ++c)
            l2v[pr][c] = (l1v[2 * pr][0][c] + l1v[2 * pr][1][c] +
                          l1v[2 * pr + 1][0][c] + l1v[2 * pr + 1][1][c]) * 0.25f;
        uint2* d2 = ((i == 0) ? pL2r + ((size_t)b << 15) : pL2t + ((size_t)q << 15))
                    + (((band << 1) + pr) << 8) + t;
        *d2 = pack_px(l2v[pr][0], l2v[pr][1], l2v[pr][2]);
    }
    float l3[3];
#pragma unroll
    for (int c = 0; c < 3; ++c) {
        float s = l2v[0][c] + l2v[1][c];
        l3[c] = (s + __shfl_xor(s, 1)) * 0.25f;
    }
    if ((t & 1) == 0) {
        uint2* d3 = ((i == 0) ? pL3r + ((size_t)b << 13) : pL3t + ((size_t)q << 13))
                    + (band << 7) + (t >> 1);
        *d3 = pack_px(l3[0], l3[1], l3[2]);
    }
}

// ---------------- packed photometric body, 4 px/thread, 32-tap burst ----------------
template <int SH>
__device__ inline float photo_scale4(int bidl, int tid,
                                     const float* __restrict__ rrF,   // SH==0
                                     const uint2* __restrict__ rrP,   // SH>0
                                     const float* __restrict__ depth,
                                     const float* __restrict__ mask,
                                     const uint2* __restrict__ tg,    // planes q=n*8+b
                                     const float* __restrict__ pose,
                                     float* __restrict__ ldsRt) {
    constexpr int h = 512 >> SH;
    constexpr int w = 1024 >> SH;
    constexpr int LOG2W = 10 - SH;
    constexpr int LP = 19 - 2 * SH;
    constexpr float inv_count = 1.0f / (8.0f * 3.0f * h * w);

    int lidx = ((bidl << 8) + tid) << 2;
    int b = lidx >> LP;  // block-uniform
    if (tid < 2) make_Rt_to(pose, b * 2 + tid, ldsRt + tid * 12);
    __syncthreads();

    int x0 = lidx & (w - 1);
    int y = (lidx >> LOG2W) & (h - 1);
    int pix = (y << LOG2W) + x0;

    float lat = -(((float)y + 0.5f) * (2.0f / (float)h) - 1.0f) * (0.5f * PI_F);
    float slat = __sinf(lat), clat = __cosf(lat);

    float4 dep4 = *(const float4*)(depth + ((size_t)b << LP) + pix);
    float dp[4] = {dep4.x, dep4.y, dep4.z, dep4.w};
    float rcv[4][3];
    if constexpr (SH == 0) {
#pragma unroll
        for (int c = 0; c < 3; ++c) {
            float4 rv = *(const float4*)(rrF + ((size_t)(b * 3 + c) << LP) + pix);
            rcv[0][c] = rv.x; rcv[1][c] = rv.y; rcv[2][c] = rv.z; rcv[3][c] = rv.w;
        }
    } else {
        const uint2* rp = rrP + ((size_t)b << LP) + pix;
        uint4 u01 = *(const uint4*)rp;
        uint4 u23 = *(const uint4*)(rp + 2);
        uint2 e0; e0.x = u01.x; e0.y = u01.y;
        uint2 e1; e1.x = u01.z; e1.y = u01.w;
        uint2 e2; e2.x = u23.x; e2.y = u23.y;
        uint2 e3; e3.x = u23.z; e3.y = u23.w;
        float3 f0 = unpack_px(e0), f1 = unpack_px(e1), f2 = unpack_px(e2), f3 = unpack_px(e3);
        rcv[0][0] = f0.x; rcv[0][1] = f0.y; rcv[0][2] = f0.z;
        rcv[1][0] = f1.x; rcv[1][1] = f1.y; rcv[1][2] = f1.z;
        rcv[2][0] = f2.x; rcv[2][1] = f2.y; rcv[2][2] = f2.z;
        rcv[3][0] = f3.x; rcv[3][1] = f3.y; rcv[3][2] = f3.z;
    }
    float m4[2][4];
#pragma unroll
    for (int n = 0; n < 2; ++n) {
        float4 mv = *(const float4*)(mask + ((size_t)(b * 2 + n) << LP) + pix);
        m4[n][0] = mv.x; m4[n][1] = mv.y; m4[n][2] = mv.z; m4[n][3] = mv.w;
    }

    const uint2* pl0 = tg + ((size_t)b << LP);
    const uint2* pl1 = tg + ((size_t)(8 + b) << LP);

    // phase A: all 8 (px,frame) groups' addresses + weights
    float wt[8][4];
    int off[8][4];
#pragma unroll
    for (int i = 0; i < 4; ++i) {
        float lon = (((float)(x0 + i) + 0.5f) * (2.0f / (float)w) - 1.0f) * PI_F;
        float sl = __sinf(lon), cl = __cosf(lon);
        float X = dp[i] * clat * sl, Y = dp[i] * slat, Z = dp[i] * clat * cl;
#pragma unroll
        for (int n = 0; n < 2; ++n) {
            const float* R = ldsRt + n * 12;
            float px = R[0] * X + R[1] * Y + R[2] * Z + R[9];
            float py = R[3] * X + R[4] * Y + R[5] * Z + R[10];
            float pz = R[6] * X + R[7] * Y + R[8] * Z + R[11];
            float rxz = sqrtf(px * px + pz * pz);
            float lon2 = fast_atan2f(px, pz);
            float lat2 = fast_atan2f(py, rxz);
            float gx = (lon2 * (1.0f / PI_F) + 1.0f) * 0.5f * (float)(w - 1);
            float gy = (lat2 * (2.0f / PI_F) + 1.0f) * 0.5f * (float)(h - 1);
            float x0f = floorf(gx), y0f = floorf(gy);
            float fx = gx - x0f, fy = gy - y0f;
            float wa = (1.0f - fx) * (1.0f - fy);
            float wb = (1.0f - fx) * fy;
            float wc = fx * (1.0f - fy);
            float wd = fx * fy;
            bool vx0 = (x0f >= 0.0f) && (x0f <= (float)(w - 1));
            bool vx1 = (x0f >= -1.0f) && (x0f <= (float)(w - 2));
            bool vy0 = (y0f >= 0.0f) && (y0f <= (float)(h - 1));
            bool vy1 = (y0f >= -1.0f) && (y0f <= (float)(h - 2));
            int xi0 = (int)fminf(fmaxf(x0f, 0.0f), (float)(w - 1));
            int xi1 = (int)fminf(fmaxf(x0f + 1.0f, 0.0f), (float)(w - 1));
            int yi0 = (int)fminf(fmaxf(y0f, 0.0f), (float)(h - 1));
            int yi1 = (int)fminf(fmaxf(y0f + 1.0f, 0.0f), (float)(h - 1));
            int g = i * 2 + n;
            wt[g][0] = (vx0 && vy0) ? wa : 0.0f;
            wt[g][1] = (vx0 && vy1) ? wb : 0.0f;
            wt[g][2] = (vx1 && vy0) ? wc : 0.0f;
            wt[g][3] = (vx1 && vy1) ? wd : 0.0f;
            off[g][0] = (yi0 << LOG2W) + xi0;
            off[g][1] = (yi1 << LOG2W) + xi0;
            off[g][2] = (yi0 << LOG2W) + xi1;
            off[g][3] = (yi1 << LOG2W) + xi1;
        }
    }
    // phase B: one 32-load burst
    uint2 tap[8][4];
#pragma unroll
    for (int g = 0; g < 8; ++g) {
        const uint2* P = (g & 1) ? pl1 : pl0;
#pragma unroll
        for (int k = 0; k < 4; ++k) tap[g][k] = P[off[g][k]];
    }
    // phase C: combine
    float acc = 0.0f;
#pragma unroll
    for (int g = 0; g < 8; ++g) {
        int i = g >> 1, n = g & 1;
        float3 ta = unpack_px(tap[g][0]);
        float3 tb = unpack_px(tap[g][1]);
        float3 tc = unpack_px(tap[g][2]);
        float3 td = unpack_px(tap[g][3]);
        float v0 = wt[g][0] * ta.x + wt[g][1] * tb.x + wt[g][2] * tc.x + wt[g][3] * td.x;
        float v1 = wt[g][0] * ta.y + wt[g][1] * tb.y + wt[g][2] * tc.y + wt[g][3] * td.y;
        float v2 = wt[g][0] * ta.z + wt[g][1] * tb.z + wt[g][2] * tc.z + wt[g][3] * td.z;
        acc += m4[n][i] * (fabsf(rcv[i][0] - v0) + fabsf(rcv[i][1] - v1) + fabsf(rcv[i][2] - v2));
    }
    return acc * inv_count;
}

__global__ __launch_bounds__(256) void photo_all_packed4(
    const float* __restrict__ rrF,
    const uint2* __restrict__ rr1, const uint2* __restrict__ rr2, const uint2* __restrict__ rr3,
    const float* __restrict__ dep0, const float* __restrict__ msk0,
    const float* __restrict__ dep1, const float* __restrict__ msk1,
    const float* __restrict__ dep2, const float* __restrict__ msk2,
    const float* __restrict__ dep3, const float* __restrict__ msk3,
    const uint2* __restrict__ packF,
    const uint2* __restrict__ pL1t, const uint2* __restrict__ pL2t, const uint2* __restrict__ pL3t,
    const float* __restrict__ pose, float* __restrict__ out) {
    __shared__ float ldsRt[24];
    __shared__ float wsum[4];
    int bid = blockIdx.x, tid = threadIdx.x;
    float acc;
    // XCD slab swizzle: blocks dispatched round-robin over 8 XCDs -> give each
    // XCD a contiguous slab (== one batch b at every scale) for L2 tap locality.
    if (bid < 4096) {
        int s = ((bid & 7) << 9) | (bid >> 3);
        acc = photo_scale4<0>(s, tid, rrF, nullptr, dep0, msk0, packF, pose, ldsRt);
    } else if (bid < 5120) {
        int t0 = bid - 4096;
        int s = ((t0 & 7) << 7) | (t0 >> 3);
        acc = photo_scale4<1>(s, tid, nullptr, rr1, dep1, msk1, pL1t, pose, ldsRt);
    } else if (bid < 5376) {
        int t0 = bid - 5120;
        int s = ((t0 & 7) << 5) | (t0 >> 3);
        acc = photo_scale4<2>(s, tid, nullptr, rr2, dep2, msk2, pL2t, pose, ldsRt);
    } else {
        int t0 = bid - 5376;
        int s = ((t0 & 7) << 3) | (t0 >> 3);
        acc = photo_scale4<3>(s, tid, nullptr, rr3, dep3, msk3, pL3t, pose, ldsRt);
    }

    for (int off = 32; off > 0; off >>= 1) acc += __shfl_down(acc, off);
    if ((tid & 63) == 0) wsum[tid >> 6] = acc;
    __syncthreads();
    if (tid == 0) atomicAdd(out, wsum[0] + wsum[1] + wsum[2] + wsum[3]);
}

// ================= fallback path (round-3 proven fp32 kernels) =================
template <int LWD>
__global__ __launch_bounds__(256) void down3_kernel(const float* __restrict__ sA,
                                                    const float* __restrict__ sB,
                                                    const float* __restrict__ sC,
                                                    float* __restrict__ dA,
                                                    float* __restrict__ dB,
                                                    float* __restrict__ dC) {
    const float* src = (blockIdx.y == 0) ? sA : (blockIdx.y == 1) ? sB : sC;
    float* dst = (blockIdx.y == 0) ? dA : (blockIdx.y == 1) ? dB : dC;
    int idx = blockIdx.x * 256 + threadIdx.x;
    constexpr int HB = LWD - 1;
    int xp = idx & ((1 << HB) - 1);
    int y = (idx >> HB) & ((1 << HB) - 1);
    int c = idx >> (2 * HB);
    const float* sp = src + ((size_t)c << (2 * LWD + 1)) + ((size_t)(2 * y) << (LWD + 1)) + 4 * xp;
    float4 r0 = *(const float4*)sp;
    float4 r1 = *(const float4*)(sp + (1 << (LWD + 1)));
    float2 d;
    d.x = 0.25f * (r0.x + r0.y + r1.x + r1.y);
    d.y = 0.25f * (r0.z + r0.w + r1.z + r1.w);
    *(float2*)(dst + ((size_t)c << (2 * LWD - 1)) + ((size_t)y << LWD) + 2 * xp) = d;
}

template <int SH>
__device__ inline float photo_scale(int bidl, int tid,
                                    const float* __restrict__ rr,
                                    const float* __restrict__ depth,
                                    const float* __restrict__ mask,
                                    const float* __restrict__ tg0,
                                    const float* __restrict__ tg1,
                                    const float* __restrict__ pose,
                                    float* __restrict__ ldsRt) {
    constexpr int h = 512 >> SH;
    constexpr int w = 1024 >> SH;
    constexpr int LOG2W = 10 - SH;
    constexpr int LP = 19 - 2 * SH;
    constexpr float inv_count = 1.0f / (8.0f * 3.0f * h * w);
    int lidx = (bidl << 8) + tid;
    int b = lidx >> LP;
    if (tid < 2) make_Rt_to(pose, b * 2 + tid, ldsRt + tid * 12);
    __syncthreads();
    int x = lidx & (w - 1);
    int y = (lidx >> LOG2W) & (h - 1);
    int pix = (y << LOG2W) + x;
    float lon = (((float)x + 0.5f) * (2.0f / (float)w) - 1.0f) * PI_F;
    float lat = -(((float)y + 0.5f) * (2.0f / (float)h) - 1.0f) * (0.5f * PI_F);
    float sl = __sinf(lon), cl = __cosf(lon);
    float slat = __sinf(lat), clat = __cosf(lat);
    float dep = depth[((size_t)b << LP) + pix];
    float X = dep * clat * sl, Y = dep * slat, Z = dep * clat * cl;
    float rc[3];
#pragma unroll
    for (int c = 0; c < 3; ++c)
        rc[c] = rr[((size_t)(b * 3 + c) << LP) + pix];
    float acc = 0.0f;
#pragma unroll
    for (int n = 0; n < 2; ++n) {
        const float* R = ldsRt + n * 12;
        float px = R[0] * X + R[1] * Y + R[2] * Z + R[9];
        float py = R[3] * X + R[4] * Y + R[5] * Z + R[10];
        float pz = R[6] * X + R[7] * Y + R[8] * Z + R[11];
        float rxz = sqrtf(px * px + pz * pz);
        float lon2 = fast_atan2f(px, pz);
        float lat2 = fast_atan2f(py, rxz);
        float gx = (lon2 * (1.0f / PI_F) + 1.0f) * 0.5f * (float)(w - 1);
        float gy = (lat2 * (2.0f / PI_F) + 1.0f) * 0.5f * (float)(h - 1);
        float x0f = floorf(gx), y0f = floorf(gy);
        float fx = gx - x0f, fy = gy - y0f;
        float wa = (1.0f - fx) * (1.0f - fy);
        float wb = (1.0f - fx) * fy;
        float wc = fx * (1.0f - fy);
        float wd = fx * fy;
        bool vx0 = (x0f >= 0.0f) && (x0f <= (float)(w - 1));
        bool vx1 = (x0f >= -1.0f) && (x0f <= (float)(w - 2));
        bool vy0 = (y0f >= 0.0f) && (y0f <= (float)(h - 1));
        bool vy1 = (y0f >= -1.0f) && (y0f <= (float)(h - 2));
        int xi0 = (int)fminf(fmaxf(x0f, 0.0f), (float)(w - 1));
        int xi1 = (int)fminf(fmaxf(x0f + 1.0f, 0.0f), (float)(w - 1));
        int yi0 = (int)fminf(fmaxf(y0f, 0.0f), (float)(h - 1));
        int yi1 = (int)fminf(fmaxf(y0f + 1.0f, 0.0f), (float)(h - 1));
        float waf = (vx0 && vy0) ? wa : 0.0f;
        float wbf = (vx0 && vy1) ? wb : 0.0f;
        float wcf = (vx1 && vy0) ? wc : 0.0f;
        float wdf = (vx1 && vy1) ? wd : 0.0f;
        int ia = (yi0 << LOG2W) + xi0;
        int ib2 = (yi1 << LOG2W) + xi0;
        int ic = (yi0 << LOG2W) + xi1;
        int id = (yi1 << LOG2W) + xi1;
        const float* tg = (n == 0) ? tg0 : tg1;
        float m = mask[((size_t)(b * 2 + n) << LP) + pix];
#pragma unroll
        for (int c = 0; c < 3; ++c) {
            const float* plane = tg + ((size_t)(b * 3 + c) << LP);
            float v = waf * plane[ia] + wbf * plane[ib2] + wcf * plane[ic] + wdf * plane[id];
            acc += m * fabsf(rc[c] - v);
        }
    }
    return acc * inv_count;
}

__global__ __launch_bounds__(256) void photo_all_kernel(
    const float* __restrict__ rr0, const float* __restrict__ dep0, const float* __restrict__ msk0,
    const float* __restrict__ tA0, const float* __restrict__ tB0,
    const float* __restrict__ rr1, const float* __restrict__ dep1, const float* __restrict__ msk1,
    const float* __restrict__ tA1, const float* __restrict__ tB1,
    const float* __restrict__ rr2, const float* __restrict__ dep2, const float* __restrict__ msk2,
    const float* __restrict__ tA2, const float* __restrict__ tB2,
    const float* __restrict__ rr3, const float* __restrict__ dep3, const float* __restrict__ msk3,
    const float* __restrict__ tA3, const float* __restrict__ tB3,
    const float* __restrict__ pose, float* __restrict__ out) {
    __shared__ float ldsRt[24];
    __shared__ float wsum[4];
    int bid = blockIdx.x, tid = threadIdx.x;
    float acc;
    if (bid < 16384)
        acc = photo_scale<0>(bid, tid, rr0, dep0, msk0, tA0, tB0, pose, ldsRt);
    else if (bid < 20480)
        acc = photo_scale<1>(bid - 16384, tid, rr1, dep1, msk1, tA1, tB1, pose, ldsRt);
    else if (bid < 21504)
        acc = photo_scale<2>(bid - 20480, tid, rr2, dep2, msk2, tA2, tB2, pose, ldsRt);
    else
        acc = photo_scale<3>(bid - 21504, tid, rr3, dep3, msk3, tA3, tB3, pose, ldsRt);
    for (int off = 32; off > 0; off >>= 1) acc += __shfl_down(acc, off);
    if ((tid & 63) == 0) wsum[tid >> 6] = acc;
    __syncthreads();
    if (tid == 0) atomicAdd(out, wsum[0] + wsum[1] + wsum[2] + wsum[3]);
}

extern "C" void kernel_launch(void* const* d_in, const int* in_sizes, int n_in,
                              void* d_out, int out_size, void* d_ws, size_t ws_size,
                              hipStream_t stream) {
    // dict order: ref_rgb, (ref_depth{i}, exp_mask{i}) i=0..3, tgt_rgb0, tgt_rgb1, pose
    const float* ref  = (const float*)d_in[0];
    const float* dep0 = (const float*)d_in[1];
    const float* msk0 = (const float*)d_in[2];
    const float* dep1 = (const float*)d_in[3];
    const float* msk1 = (const float*)d_in[4];
    const float* dep2 = (const float*)d_in[5];
    const float* msk2 = (const float*)d_in[6];
    const float* dep3 = (const float*)d_in[7];
    const float* msk3 = (const float*)d_in[8];
    const float* tgt0 = (const float*)d_in[9];
    const float* tgt1 = (const float*)d_in[10];
    const float* pose = (const float*)d_in[11];
    float* out = (float*)d_out;

    const size_t E_F   = (size_t)16 << 19;
    const size_t E_L1t = (size_t)16 << 17;
    const size_t E_L2t = (size_t)16 << 15;
    const size_t E_L3t = (size_t)16 << 13;
    const size_t E_L1r = (size_t)8 << 17;
    const size_t E_L2r = (size_t)8 << 15;
    const size_t E_L3r = (size_t)8 << 13;
    const size_t NEED_PACKED = (E_F + E_L1t + E_L2t + E_L3t + E_L1r + E_L2r + E_L3r) * sizeof(uint2);

    const size_t L1 = (size_t)24 * 256 * 512;
    const size_t L2 = (size_t)24 * 128 * 256;
    const size_t L3 = (size_t)24 * 64 * 128;
    const size_t NEED_A = 3 * (L1 + L2 + L3) * sizeof(float);

    if (ws_size >= NEED_PACKED) {
        uint2* p = (uint2*)d_ws;
        uint2* packF = p; p += E_F;
        uint2* pL1t = p; p += E_L1t;
        uint2* pL2t = p; p += E_L2t;
        uint2* pL3t = p; p += E_L3t;
        uint2* pL1r = p; p += E_L1r;
        uint2* pL2r = p; p += E_L2r;
        uint2* pL3r = p; p += E_L3r;

        prep_kernel<<<1536, 256, 0, stream>>>(ref, tgt0, tgt1, packF,
                                              pL1t, pL2t, pL3t, pL1r, pL2r, pL3r, out);
        photo_all_packed4<<<5440, 256, 0, stream>>>(
            ref, pL1r, pL2r, pL3r,
            dep0, msk0, dep1, msk1, dep2, msk2, dep3, msk3,
            packF, pL1t, pL2t, pL3t, pose, out);
    } else if (ws_size >= NEED_A) {
        hipMemsetAsync(out, 0, sizeof(float), stream);
        float* p = (float*)d_ws;
        float* ref_l1 = p; p += L1;
        float* ref_l2 = p; p += L2;
        float* ref_l3 = p; p += L3;
        float* t0_l1 = p; p += L1;
        float* t0_l2 = p; p += L2;
        float* t0_l3 = p; p += L3;
        float* t1_l1 = p; p += L1;
        float* t1_l2 = p; p += L2;
        float* t1_l3 = p; p += L3;
        down3_kernel<9><<<dim3((24 << 16) / 256, 3), 256, 0, stream>>>(
            ref, tgt0, tgt1, ref_l1, t0_l1, t1_l1);
        down3_kernel<8><<<dim3((24 << 14) / 256, 3), 256, 0, stream>>>(
            ref_l1, t0_l1, t1_l1, ref_l2, t0_l2, t1_l2);
        down3_kernel<7><<<dim3((24 << 12) / 256, 3), 256, 0, stream>>>(
            ref_l2, t0_l2, t1_l2, ref_l3, t0_l3, t1_l3);
        photo_all_kernel<<<21760, 256, 0, stream>>>(
            ref, dep0, msk0, tgt0, tgt1,
            ref_l1, dep1, msk1, t0_l1, t1_l1,
            ref_l2, dep2, msk2, t0_l2, t1_l2,
            ref_l3, dep3, msk3, t0_l3, t1_l3,
            pose, out);
    }
}